// Round 1
// baseline (506.192 us; speedup 1.0000x reference)
//
#include <hip/hip_runtime.h>
#include <hip/hip_bf16.h>

typedef __bf16 bf16_t;
typedef __bf16 bf16x8 __attribute__((ext_vector_type(8)));
typedef __bf16 bf16x4 __attribute__((ext_vector_type(4)));
typedef float  f32x4  __attribute__((ext_vector_type(4)));

#define B_ 8
#define C_ 256
#define L_ 4096
#define M_ 2048

__device__ __forceinline__ const bf16x8* ldg8(const bf16_t* p) {
    return reinterpret_cast<const bf16x8*>(p);
}

// ---------------- kernel 1: weight conversion f32 -> bf16 ----------------
__global__ __launch_bounds__(256) void conv_w_kernel(
    const float* __restrict__ Wq, const float* __restrict__ Wk, const float* __restrict__ Wv,
    bf16_t* __restrict__ Wqb, bf16_t* __restrict__ Wkb, bf16_t* __restrict__ Wvb) {
    int idx = blockIdx.x * 256 + threadIdx.x;      // 0..196607
    int which = idx >> 16;
    int off = idx & 65535;
    const float* src = (which == 0) ? Wq : ((which == 1) ? Wk : Wv);
    bf16_t* dst = (which == 0) ? Wqb : ((which == 1) ? Wkb : Wvb);
    dst[off] = (bf16_t)src[off];
}

// ---------------- kernel 2: x -> xbt [B,L,C] bf16 ; xh -> xhbt [B,M,C] bf16 ----------------
__global__ __launch_bounds__(256) void prep_x_kernel(
    const float* __restrict__ x, bf16_t* __restrict__ xbt, bf16_t* __restrict__ xhbt) {
    __shared__ float tile[64][65];   // [c][l]
    const float INV_SQRT2 = 0.70710678118654752440f;
    int b = blockIdx.z, c0 = blockIdx.y * 64, l0 = blockIdx.x * 64;
    int t = threadIdx.x;
    int tr = t >> 6;      // 0..3
    int tc = t & 63;
    const float* xp = x + ((size_t)(b * C_ + c0) * L_) + l0;
#pragma unroll
    for (int i = 0; i < 16; ++i) {
        int row = i * 4 + tr;
        tile[row][tc] = xp[(size_t)row * L_ + tc];
    }
    __syncthreads();
    // xbt[b][l0+lr][c0+tc] = x[b][c0+tc][l0+lr]
    bf16_t* xo = xbt + ((size_t)(b * L_ + l0) * C_) + c0;
#pragma unroll
    for (int i = 0; i < 16; ++i) {
        int lr = i * 4 + tr;
        xo[(size_t)lr * C_ + tc] = (bf16_t)tile[tc][lr];
    }
    // xh[b][c][m] = (x[..2m] - x[..2m+1])*inv_sqrt2 ; store transposed [m][c]
    int m0 = l0 >> 1;
    bf16_t* xho = xhbt + ((size_t)(b * M_ + m0) * C_) + c0;
#pragma unroll
    for (int i = 0; i < 8; ++i) {
        int mr = i * 4 + tr;
        float v = (tile[tc][2 * mr] - tile[tc][2 * mr + 1]) * INV_SQRT2;
        xho[(size_t)mr * C_ + tc] = (bf16_t)v;
    }
}

// ---------------- kernel 3: out[b][n][o] = sum_c A[b][n][c] * W[o][c] + bias[o] ----------------
// A: bf16 [B][N][C], W: bf16 [C][C]; used for q' (A=xbt,N=L) and k' (A=xhbt,N=M)
__global__ __launch_bounds__(256) void proj_nk_kernel(
    const bf16_t* __restrict__ A, const bf16_t* __restrict__ W,
    const float* __restrict__ bias, bf16_t* __restrict__ out, int N) {
    int b = blockIdx.y;
    int wave = threadIdx.x >> 6, lane = threadIdx.x & 63;
    int l15 = lane & 15, g = lane >> 4;
    int n0 = blockIdx.x * 64 + wave * 16;

    const bf16_t* Ap = A + ((size_t)(b * N + n0 + l15) * C_) + g * 8;
    bf16x8 af[8];
#pragma unroll
    for (int k = 0; k < 8; ++k) af[k] = *ldg8(Ap + k * 32);

    f32x4 acc[16];
#pragma unroll
    for (int ot = 0; ot < 16; ++ot) {
        float bb = bias[ot * 16 + l15];
        acc[ot][0] = bb; acc[ot][1] = bb; acc[ot][2] = bb; acc[ot][3] = bb;
    }
#pragma unroll
    for (int ot = 0; ot < 16; ++ot) {
        const bf16_t* Wp = W + ((size_t)(ot * 16 + l15) * C_) + g * 8;
#pragma unroll
        for (int k = 0; k < 8; ++k) {
            bf16x8 bfr = *ldg8(Wp + k * 32);
            acc[ot] = __builtin_amdgcn_mfma_f32_16x16x32_bf16(af[k], bfr, acc[ot], 0, 0, 0);
        }
    }
    bf16_t* op = out + ((size_t)(b * N + n0 + g * 4) * C_);
#pragma unroll
    for (int ot = 0; ot < 16; ++ot)
#pragma unroll
        for (int r = 0; r < 4; ++r)
            op[(size_t)r * C_ + ot * 16 + l15] = (bf16_t)acc[ot][r];
}

// ---------------- kernel 4: v'[b][o][m] = sum_c Wv[o][c] * xhbt[b][m][c] + bv[o] ----------------
__global__ __launch_bounds__(256) void proj_v_kernel(
    const bf16_t* __restrict__ xhbt, const bf16_t* __restrict__ W,
    const float* __restrict__ bias, bf16_t* __restrict__ out) {
    int b = blockIdx.z;
    int wave = threadIdx.x >> 6, lane = threadIdx.x & 63;
    int l15 = lane & 15, g = lane >> 4;
    int o0 = blockIdx.y * 64 + wave * 16;
    int m0 = blockIdx.x * 256;

    const bf16_t* Wp = W + ((size_t)(o0 + l15) * C_) + g * 8;
    bf16x8 af[8];
#pragma unroll
    for (int k = 0; k < 8; ++k) af[k] = *ldg8(Wp + k * 32);

    float bv4[4];
#pragma unroll
    for (int r = 0; r < 4; ++r) bv4[r] = bias[o0 + g * 4 + r];

    f32x4 acc[16];
#pragma unroll
    for (int mt = 0; mt < 16; ++mt) {
        acc[mt][0] = bv4[0]; acc[mt][1] = bv4[1]; acc[mt][2] = bv4[2]; acc[mt][3] = bv4[3];
    }
#pragma unroll
    for (int mt = 0; mt < 16; ++mt) {
        const bf16_t* Bp = xhbt + ((size_t)(b * M_ + m0 + mt * 16 + l15) * C_) + g * 8;
#pragma unroll
        for (int k = 0; k < 8; ++k) {
            bf16x8 bfr = *ldg8(Bp + k * 32);
            acc[mt] = __builtin_amdgcn_mfma_f32_16x16x32_bf16(af[k], bfr, acc[mt], 0, 0, 0);
        }
    }
    bf16_t* op = out + ((size_t)(b * C_ + o0 + g * 4) * M_) + m0;
#pragma unroll
    for (int mt = 0; mt < 16; ++mt)
#pragma unroll
        for (int r = 0; r < 4; ++r)
            op[(size_t)r * M_ + mt * 16 + l15] = (bf16_t)acc[mt][r];
}

// ---------------- kernel 5: flash attention + gate + residual ----------------
// S = K'·q (D[m,l]), softmax over m (rows), yh = V'·P (D[c,l]); out[b][c][l] = yh*g + x
#define KT 32
__global__ __launch_bounds__(256) void attn_kernel(
    const bf16_t* __restrict__ qb, const bf16_t* __restrict__ kb, const bf16_t* __restrict__ vb,
    const float* __restrict__ x, const float* __restrict__ gate, float* __restrict__ out) {
    // LDS: K [32][256] bf16 swizzled (16384B) ; V [256][34] bf16 (17408B) ; P 4x[16][34] bf16 (4352B)
    __shared__ __align__(16) char smem[16384 + 17408 + 4352];
    char* Ks = smem;
    char* Vs = smem + 16384;
    char* Ps = smem + 16384 + 17408;

    int b = blockIdx.y;
    int t = threadIdx.x;
    int wave = t >> 6, lane = t & 63;
    int l15 = lane & 15, g = lane >> 4;
    int l0 = blockIdx.x * 64 + wave * 16;
    int lq = l0 + l15;

    // Q fragments (B-operand layout): rows of q'[B,L,C]
    bf16x8 qf[8];
    const bf16_t* Qp = qb + ((size_t)(b * L_ + lq) * C_) + g * 8;
#pragma unroll
    for (int k = 0; k < 8; ++k) qf[k] = *ldg8(Qp + k * 32);

    f32x4 acc[16];
#pragma unroll
    for (int ct = 0; ct < 16; ++ct) { acc[ct][0] = 0.f; acc[ct][1] = 0.f; acc[ct][2] = 0.f; acc[ct][3] = 0.f; }
    float m_run = -INFINITY, l_run = 0.f;

    // staging coords
    int km = t >> 5;            // 0..7
    int kc16 = (t & 31) * 16;   // byte col within K row
    const bf16_t* Kbase = kb + (size_t)b * M_ * C_;
    int vc = t >> 2;            // 0..63
    int vchunk = (t & 3) * 8;   // elements within V row
    const bf16_t* Vbase = vb + (size_t)b * C_ * M_;
    char* Pw = Ps + wave * 1088;

    for (int kt = 0; kt < M_ / KT; ++kt) {
        int m0 = kt * KT;
        __syncthreads();
        // stage K: [m][c] with XOR swizzle byte ^= (m&7)<<4
#pragma unroll
        for (int i = 0; i < 4; ++i) {
            int m = i * 8 + km;
            bf16x8 v = *ldg8(Kbase + (size_t)(m0 + m) * C_ + (kc16 >> 1));
            int off = m * 512 + (kc16 ^ ((m & 7) << 4));
            *reinterpret_cast<bf16x8*>(Ks + off) = v;
        }
        // stage V: [c][m] stride 34 elements
#pragma unroll
        for (int i = 0; i < 4; ++i) {
            int c = i * 64 + vc;
            bf16x8 v = *ldg8(Vbase + (size_t)c * M_ + m0 + vchunk);
            *reinterpret_cast<bf16x8*>(Vs + c * 68 + vchunk * 2) = v;
        }
        __syncthreads();

        // S = K' x q : D[m,l]
        f32x4 s[2];
        s[0][0]=0.f; s[0][1]=0.f; s[0][2]=0.f; s[0][3]=0.f;
        s[1][0]=0.f; s[1][1]=0.f; s[1][2]=0.f; s[1][3]=0.f;
#pragma unroll
        for (int msub = 0; msub < 2; ++msub) {
            int m = msub * 16 + l15;
            int rowoff = m * 512;
            int sw = (m & 7) << 4;
#pragma unroll
            for (int k = 0; k < 8; ++k) {
                int cbyte = (k * 32 + g * 8) * 2;
                bf16x8 a = *reinterpret_cast<const bf16x8*>(Ks + rowoff + (cbyte ^ sw));
                s[msub] = __builtin_amdgcn_mfma_f32_16x16x32_bf16(a, qf[k], s[msub], 0, 0, 0);
            }
        }
        // softmax (over m = rows). per-lane col l is fixed => scalar state
        float pv[8];
        float tm = -INFINITY;
#pragma unroll
        for (int msub = 0; msub < 2; ++msub)
#pragma unroll
            for (int r = 0; r < 4; ++r) {
                float val = s[msub][r] * 0.0625f;
                pv[msub * 4 + r] = val;
                tm = fmaxf(tm, val);
            }
        tm = fmaxf(tm, __shfl_xor(tm, 16));
        tm = fmaxf(tm, __shfl_xor(tm, 32));
        float m_new = fmaxf(m_run, tm);
        float corr = __expf(m_run - m_new);
        float rs = 0.f;
#pragma unroll
        for (int i = 0; i < 8; ++i) { pv[i] = __expf(pv[i] - m_new); rs += pv[i]; }
        rs += __shfl_xor(rs, 16);
        rs += __shfl_xor(rs, 32);
        l_run = l_run * corr + rs;
        m_run = m_new;
#pragma unroll
        for (int ct = 0; ct < 16; ++ct) {
            acc[ct][0] *= corr; acc[ct][1] *= corr; acc[ct][2] *= corr; acc[ct][3] *= corr;
        }
        // write P[l][m] (bf16, packed 4 = 8B)
#pragma unroll
        for (int msub = 0; msub < 2; ++msub) {
            bf16x4 pk;
#pragma unroll
            for (int r = 0; r < 4; ++r) pk[r] = (bf16_t)pv[msub * 4 + r];
            int off = (l15 * 34 + msub * 16 + g * 4) * 2;
            *reinterpret_cast<bf16x4*>(Pw + off) = pk;
        }
        // PV: D[c,l] += V'[c,m] * P[m,l]
        bf16x8 pb = *reinterpret_cast<const bf16x8*>(Pw + (l15 * 34 + g * 8) * 2);
#pragma unroll
        for (int ct = 0; ct < 16; ++ct) {
            bf16x8 a = *reinterpret_cast<const bf16x8*>(Vs + ((ct * 16 + l15) * 34 + g * 8) * 2);
            acc[ct] = __builtin_amdgcn_mfma_f32_16x16x32_bf16(a, pb, acc[ct], 0, 0, 0);
        }
    }

    // epilogue: out[b][c][l] = acc/l_run * tanh(gate) + x
    float gt = tanhf(gate[0]);
    float inv = gt / l_run;
    const float* xp = x + (size_t)b * C_ * L_;
    float* op = out + (size_t)b * C_ * L_;
    int lcol = l0 + l15;
#pragma unroll
    for (int ct = 0; ct < 16; ++ct)
#pragma unroll
        for (int r = 0; r < 4; ++r) {
            int c = ct * 16 + g * 4 + r;
            size_t idx = (size_t)c * L_ + lcol;
            op[idx] = acc[ct][r] * inv + xp[idx];
        }
}

extern "C" void kernel_launch(void* const* d_in, const int* in_sizes, int n_in,
                              void* d_out, int out_size, void* d_ws, size_t ws_size,
                              hipStream_t stream) {
    const float* x    = (const float*)d_in[0];
    const float* Wq   = (const float*)d_in[1];
    const float* bq   = (const float*)d_in[2];
    const float* Wk   = (const float*)d_in[3];
    const float* bk   = (const float*)d_in[4];
    const float* Wv   = (const float*)d_in[5];
    const float* bv   = (const float*)d_in[6];
    const float* gate = (const float*)d_in[7];
    float* out = (float*)d_out;

    char* ws = (char*)d_ws;
    const size_t szW   = (size_t)C_ * C_ * 2;          // 131072
    const size_t szXbt = (size_t)B_ * L_ * C_ * 2;     // 16777216
    const size_t szXh  = (size_t)B_ * M_ * C_ * 2;     // 8388608
    bf16_t* Wqb  = (bf16_t*)(ws);
    bf16_t* Wkb  = (bf16_t*)(ws + szW);
    bf16_t* Wvb  = (bf16_t*)(ws + 2 * szW);
    bf16_t* xbt  = (bf16_t*)(ws + 3 * szW);
    bf16_t* xhbt = (bf16_t*)(ws + 3 * szW + szXbt);
    bf16_t* qb   = (bf16_t*)(ws + 3 * szW + szXbt + szXh);
    bf16_t* kb   = (bf16_t*)(ws + 3 * szW + 2 * szXbt + szXh);
    bf16_t* vb   = (bf16_t*)(ws + 3 * szW + 2 * szXbt + 2 * szXh);

    conv_w_kernel<<<768, 256, 0, stream>>>(Wq, Wk, Wv, Wqb, Wkb, Wvb);
    prep_x_kernel<<<dim3(L_ / 64, C_ / 64, B_), 256, 0, stream>>>(x, xbt, xhbt);
    proj_nk_kernel<<<dim3(L_ / 64, B_), 256, 0, stream>>>(xbt, Wqb, bq, qb, L_);
    proj_nk_kernel<<<dim3(M_ / 64, B_), 256, 0, stream>>>(xhbt, Wkb, bk, kb, M_);
    proj_v_kernel<<<dim3(M_ / 256, C_ / 64, B_), 256, 0, stream>>>(xhbt, Wvb, bv, vb);
    attn_kernel<<<dim3(L_ / 64, B_), 256, 0, stream>>>(qb, kb, vb, x, gate, out);
}

// Round 2
// 205.810 us; speedup vs baseline: 2.4595x; 2.4595x over previous
//
#include <hip/hip_runtime.h>
#include <hip/hip_bf16.h>

typedef __bf16 bf16_t;
typedef __bf16 bf16x8 __attribute__((ext_vector_type(8)));
typedef __bf16 bf16x4 __attribute__((ext_vector_type(4)));
typedef float  f32x4  __attribute__((ext_vector_type(4)));

#define B_ 8
#define C_ 256
#define L_ 4096
#define M_ 2048

__device__ __forceinline__ const bf16x8* ldg8(const bf16_t* p) {
    return reinterpret_cast<const bf16x8*>(p);
}

typedef __attribute__((address_space(3))) void as3_void;
typedef __attribute__((address_space(1))) const void as1_cvoid;

__device__ __forceinline__ void gload_lds16(const void* g, void* l) {
    __builtin_amdgcn_global_load_lds((as1_cvoid*)g, (as3_void*)l, 16, 0, 0);
}

// ---------------- kernel 1: weight conversion f32 -> bf16 ----------------
__global__ __launch_bounds__(256) void conv_w_kernel(
    const float* __restrict__ Wq, const float* __restrict__ Wk, const float* __restrict__ Wv,
    bf16_t* __restrict__ Wqb, bf16_t* __restrict__ Wkb, bf16_t* __restrict__ Wvb) {
    int idx = blockIdx.x * 256 + threadIdx.x;      // 0..196607
    int which = idx >> 16;
    int off = idx & 65535;
    const float* src = (which == 0) ? Wq : ((which == 1) ? Wk : Wv);
    bf16_t* dst = (which == 0) ? Wqb : ((which == 1) ? Wkb : Wvb);
    dst[off] = (bf16_t)src[off];
}

// ---------------- kernel 2: x -> xbt [B,L,C] bf16 ; xh -> xhbt [B,M,C] bf16 ----------------
__global__ __launch_bounds__(256) void prep_x_kernel(
    const float* __restrict__ x, bf16_t* __restrict__ xbt, bf16_t* __restrict__ xhbt) {
    __shared__ float tile[64][65];   // [c][l]
    const float INV_SQRT2 = 0.70710678118654752440f;
    int b = blockIdx.z, c0 = blockIdx.y * 64, l0 = blockIdx.x * 64;
    int t = threadIdx.x;
    int tr = t >> 6;      // 0..3
    int tc = t & 63;
    const float* xp = x + ((size_t)(b * C_ + c0) * L_) + l0;
#pragma unroll
    for (int i = 0; i < 16; ++i) {
        int row = i * 4 + tr;
        tile[row][tc] = xp[(size_t)row * L_ + tc];
    }
    __syncthreads();
    // xbt[b][l0+lr][c0+tc] = x[b][c0+tc][l0+lr]
    bf16_t* xo = xbt + ((size_t)(b * L_ + l0) * C_) + c0;
#pragma unroll
    for (int i = 0; i < 16; ++i) {
        int lr = i * 4 + tr;
        xo[(size_t)lr * C_ + tc] = (bf16_t)tile[tc][lr];
    }
    // xh[b][c][m] = (x[..2m] - x[..2m+1])*inv_sqrt2 ; store transposed [m][c]
    int m0 = l0 >> 1;
    bf16_t* xho = xhbt + ((size_t)(b * M_ + m0) * C_) + c0;
#pragma unroll
    for (int i = 0; i < 8; ++i) {
        int mr = i * 4 + tr;
        float v = (tile[tc][2 * mr] - tile[tc][2 * mr + 1]) * INV_SQRT2;
        xho[(size_t)mr * C_ + tc] = (bf16_t)v;
    }
}

// ---------------- kernel 3: out[b][n][o] = sum_c A[b][n][c] * W[o][c] + bias[o] ----------------
__global__ __launch_bounds__(256) void proj_nk_kernel(
    const bf16_t* __restrict__ A, const bf16_t* __restrict__ W,
    const float* __restrict__ bias, bf16_t* __restrict__ out, int N) {
    int b = blockIdx.y;
    int wave = threadIdx.x >> 6, lane = threadIdx.x & 63;
    int l15 = lane & 15, g = lane >> 4;
    int n0 = blockIdx.x * 64 + wave * 16;

    const bf16_t* Ap = A + ((size_t)(b * N + n0 + l15) * C_) + g * 8;
    bf16x8 af[8];
#pragma unroll
    for (int k = 0; k < 8; ++k) af[k] = *ldg8(Ap + k * 32);

    f32x4 acc[16];
#pragma unroll
    for (int ot = 0; ot < 16; ++ot) {
        float bb = bias[ot * 16 + l15];
        acc[ot][0] = bb; acc[ot][1] = bb; acc[ot][2] = bb; acc[ot][3] = bb;
    }
#pragma unroll
    for (int ot = 0; ot < 16; ++ot) {
        const bf16_t* Wp = W + ((size_t)(ot * 16 + l15) * C_) + g * 8;
#pragma unroll
        for (int k = 0; k < 8; ++k) {
            bf16x8 bfr = *ldg8(Wp + k * 32);
            acc[ot] = __builtin_amdgcn_mfma_f32_16x16x32_bf16(af[k], bfr, acc[ot], 0, 0, 0);
        }
    }
    bf16_t* op = out + ((size_t)(b * N + n0 + g * 4) * C_);
#pragma unroll
    for (int ot = 0; ot < 16; ++ot)
#pragma unroll
        for (int r = 0; r < 4; ++r)
            op[(size_t)r * C_ + ot * 16 + l15] = (bf16_t)acc[ot][r];
}

// ---------------- kernel 4: v'[b][o][m] = sum_c Wv[o][c] * xhbt[b][m][c] + bv[o] ----------------
__global__ __launch_bounds__(256) void proj_v_kernel(
    const bf16_t* __restrict__ xhbt, const bf16_t* __restrict__ W,
    const float* __restrict__ bias, bf16_t* __restrict__ out) {
    int b = blockIdx.z;
    int wave = threadIdx.x >> 6, lane = threadIdx.x & 63;
    int l15 = lane & 15, g = lane >> 4;
    int o0 = blockIdx.y * 64 + wave * 16;
    int m0 = blockIdx.x * 256;

    const bf16_t* Wp = W + ((size_t)(o0 + l15) * C_) + g * 8;
    bf16x8 af[8];
#pragma unroll
    for (int k = 0; k < 8; ++k) af[k] = *ldg8(Wp + k * 32);

    float bv4[4];
#pragma unroll
    for (int r = 0; r < 4; ++r) bv4[r] = bias[o0 + g * 4 + r];

    f32x4 acc[16];
#pragma unroll
    for (int mt = 0; mt < 16; ++mt) {
        acc[mt][0] = bv4[0]; acc[mt][1] = bv4[1]; acc[mt][2] = bv4[2]; acc[mt][3] = bv4[3];
    }
#pragma unroll
    for (int mt = 0; mt < 16; ++mt) {
        const bf16_t* Bp = xhbt + ((size_t)(b * M_ + m0 + mt * 16 + l15) * C_) + g * 8;
#pragma unroll
        for (int k = 0; k < 8; ++k) {
            bf16x8 bfr = *ldg8(Bp + k * 32);
            acc[mt] = __builtin_amdgcn_mfma_f32_16x16x32_bf16(af[k], bfr, acc[mt], 0, 0, 0);
        }
    }
    bf16_t* op = out + ((size_t)(b * C_ + o0 + g * 4) * M_) + m0;
#pragma unroll
    for (int mt = 0; mt < 16; ++mt)
#pragma unroll
        for (int r = 0; r < 4; ++r)
            op[(size_t)r * M_ + mt * 16 + l15] = (bf16_t)acc[mt][r];
}

// ---------------- kernel 5: flash attention + gate + residual ----------------
// 512 threads (8 waves), Br=128 queries/block (16/wave), KT=64 keys per tile.
// K double-buffered in LDS (global_load_lds, pre-swizzled source), V single-buffered
// staged during S-phase, P per-wave in LDS. All LDS reads XOR-swizzled conflict-free.
#define KT 64
#define NT (M_ / KT)   // 32

__global__ __launch_bounds__(512, 2) void attn_kernel(
    const bf16_t* __restrict__ qb, const bf16_t* __restrict__ kb, const bf16_t* __restrict__ vb,
    const float* __restrict__ x, const float* __restrict__ gate, float* __restrict__ out) {
    // LDS: K 2x[64][512B] = 65536 ; V [256][128B] = 32768 ; P 8x[16][128B] = 16384
    __shared__ __align__(16) char smem[65536 + 32768 + 16384];
    char* Ks = smem;
    char* Vs = smem + 65536;
    char* Ps = smem + 65536 + 32768;

    const int t = threadIdx.x;
    const int wave = t >> 6, lane = t & 63;
    const int l15 = lane & 15, g = lane >> 4;
    const int bid = blockIdx.x;
    const int b = bid & 7;          // batch -> XCD affinity (round-robin dispatch)
    const int lt = bid >> 3;
    const int l0 = lt * 128 + wave * 16;

    // Q fragments (B-operand): rows of q'[B,L,C]
    bf16x8 qf[8];
    const bf16_t* Qp = qb + ((size_t)(b * L_ + l0 + l15) * C_) + g * 8;
#pragma unroll
    for (int k = 0; k < 8; ++k) qf[k] = *ldg8(Qp + k * 32);

    f32x4 acc[16];
#pragma unroll
    for (int ct = 0; ct < 16; ++ct) { acc[ct][0] = 0.f; acc[ct][1] = 0.f; acc[ct][2] = 0.f; acc[ct][3] = 0.f; }
    float m_run = -INFINITY, l_run = 0.f;

    // ---- staging geometry (global source pre-swizzled, LDS dest linear) ----
    const char* Kg = (const char*)(kb + (size_t)b * M_ * C_);
    const char* Vg = (const char*)(vb + (size_t)b * C_ * M_);
    int ksrc[4], kldsoff[4];
    int vsrc[4], vldsoff[4];
#pragma unroll
    for (int i = 0; i < 4; ++i) {
        int chunk = i * 8 + wave;                 // 0..31 (1KB LDS chunks)
        int mr = chunk * 2 + (lane >> 5);         // K row 0..63
        ksrc[i] = mr * 512 + (((lane & 31) * 16) ^ ((mr & 7) << 4));
        kldsoff[i] = chunk * 1024;
        int c = chunk * 8 + (lane >> 3);          // V row 0..255
        vsrc[i] = c * (M_ * 2) + (((lane & 7) * 16) ^ ((c & 7) << 4));
        vldsoff[i] = chunk * 1024;
    }
    char* Pw = Ps + wave * 2048;
    const int swl = (l15 & 7) << 4;

    // ---- prologue: stage K tile 0 into buffer 0 ----
#pragma unroll
    for (int i = 0; i < 4; ++i)
        gload_lds16(Kg + ksrc[i], Ks + kldsoff[i]);
    asm volatile("s_waitcnt vmcnt(0)" ::: "memory");
    __builtin_amdgcn_s_barrier();
    asm volatile("" ::: "memory");

    int cur = 0;
    for (int kt = 0; kt < NT; ++kt) {
        // stage V[kt]; prefetch K[kt+1] into other buffer
#pragma unroll
        for (int i = 0; i < 4; ++i)
            gload_lds16(Vg + kt * (KT * 2) + vsrc[i], Vs + vldsoff[i]);
        if (kt + 1 < NT) {
            const char* Kn = Kg + (size_t)(kt + 1) * (KT * C_ * 2);
            char* Kd = Ks + ((cur ^ 1) * 32768);
#pragma unroll
            for (int i = 0; i < 4; ++i)
                gload_lds16(Kn + ksrc[i], Kd + kldsoff[i]);
        }

        // ---- S = K'·q : D[m,l] ----
        const char* Kc = Ks + cur * 32768;
        f32x4 s4[4];
#pragma unroll
        for (int msub = 0; msub < 4; ++msub) { s4[msub][0] = 0.f; s4[msub][1] = 0.f; s4[msub][2] = 0.f; s4[msub][3] = 0.f; }
#pragma unroll
        for (int k = 0; k < 8; ++k) {
            int cb = k * 64 + g * 16;
#pragma unroll
            for (int msub = 0; msub < 4; ++msub) {
                int m = msub * 16 + l15;
                bf16x8 a = *reinterpret_cast<const bf16x8*>(Kc + m * 512 + (cb ^ ((m & 7) << 4)));
                s4[msub] = __builtin_amdgcn_mfma_f32_16x16x32_bf16(a, qf[k], s4[msub], 0, 0, 0);
            }
        }

        // ---- online softmax over m (per-lane column l is fixed) ----
        float pv[16];
        float tm = -INFINITY;
#pragma unroll
        for (int msub = 0; msub < 4; ++msub)
#pragma unroll
            for (int r = 0; r < 4; ++r) {
                float val = s4[msub][r] * 0.0625f;
                pv[msub * 4 + r] = val;
                tm = fmaxf(tm, val);
            }
        tm = fmaxf(tm, __shfl_xor(tm, 16));
        tm = fmaxf(tm, __shfl_xor(tm, 32));
        float m_new = fmaxf(m_run, tm);
        float corr = __expf(m_run - m_new);
        float rs = 0.f;
#pragma unroll
        for (int i = 0; i < 16; ++i) { pv[i] = __expf(pv[i] - m_new); rs += pv[i]; }
        rs += __shfl_xor(rs, 16);
        rs += __shfl_xor(rs, 32);
        l_run = l_run * corr + rs;
        m_run = m_new;
#pragma unroll
        for (int ct = 0; ct < 16; ++ct) {
            acc[ct][0] *= corr; acc[ct][1] *= corr; acc[ct][2] *= corr; acc[ct][3] *= corr;
        }

        // ---- write P^T[l][m] (bf16, swizzled) ----
#pragma unroll
        for (int msub = 0; msub < 4; ++msub) {
            bf16x4 pk;
#pragma unroll
            for (int r = 0; r < 4; ++r) pk[r] = (bf16_t)pv[msub * 4 + r];
            int mb = msub * 32 + g * 8;
            *reinterpret_cast<bf16x4*>(Pw + l15 * 128 + (mb ^ swl)) = pk;
        }

        // wait for V (keep K[kt+1] in flight), then barrier
        if (kt + 1 < NT) { asm volatile("s_waitcnt vmcnt(4)" ::: "memory"); }
        else             { asm volatile("s_waitcnt vmcnt(0)" ::: "memory"); }
        __builtin_amdgcn_s_barrier();
        asm volatile("" ::: "memory");

        // ---- PV: D[c,l] += V'[c,m] * P[m,l] ----
#pragma unroll
        for (int ks = 0; ks < 2; ++ks) {
            int mb = ks * 64 + g * 16;
            bf16x8 pb = *reinterpret_cast<const bf16x8*>(Pw + l15 * 128 + (mb ^ swl));
#pragma unroll
            for (int ct = 0; ct < 16; ++ct) {
                int c = ct * 16 + l15;
                bf16x8 a = *reinterpret_cast<const bf16x8*>(Vs + c * 128 + (mb ^ swl));
                acc[ct] = __builtin_amdgcn_mfma_f32_16x16x32_bf16(a, pb, acc[ct], 0, 0, 0);
            }
        }

        // drain K prefetch; barrier before overwriting Vs / reading new K buffer
        asm volatile("s_waitcnt vmcnt(0)" ::: "memory");
        __builtin_amdgcn_s_barrier();
        asm volatile("" ::: "memory");
        cur ^= 1;
    }

    // ---- epilogue: out[b][c][l] = acc/l_run * tanh(gate) + x ----
    float gt = tanhf(gate[0]);
    float inv = gt / l_run;
    const float* xp = x + (size_t)b * C_ * L_;
    float* op = out + (size_t)b * C_ * L_;
    int lcol = l0 + l15;
#pragma unroll
    for (int ct = 0; ct < 16; ++ct)
#pragma unroll
        for (int r = 0; r < 4; ++r) {
            int c = ct * 16 + g * 4 + r;
            size_t idx = (size_t)c * L_ + lcol;
            op[idx] = acc[ct][r] * inv + xp[idx];
        }
}

extern "C" void kernel_launch(void* const* d_in, const int* in_sizes, int n_in,
                              void* d_out, int out_size, void* d_ws, size_t ws_size,
                              hipStream_t stream) {
    const float* x    = (const float*)d_in[0];
    const float* Wq   = (const float*)d_in[1];
    const float* bq   = (const float*)d_in[2];
    const float* Wk   = (const float*)d_in[3];
    const float* bk   = (const float*)d_in[4];
    const float* Wv   = (const float*)d_in[5];
    const float* bv   = (const float*)d_in[6];
    const float* gate = (const float*)d_in[7];
    float* out = (float*)d_out;

    char* ws = (char*)d_ws;
    const size_t szW   = (size_t)C_ * C_ * 2;          // 131072
    const size_t szXbt = (size_t)B_ * L_ * C_ * 2;     // 16777216
    const size_t szXh  = (size_t)B_ * M_ * C_ * 2;     // 8388608
    bf16_t* Wqb  = (bf16_t*)(ws);
    bf16_t* Wkb  = (bf16_t*)(ws + szW);
    bf16_t* Wvb  = (bf16_t*)(ws + 2 * szW);
    bf16_t* xbt  = (bf16_t*)(ws + 3 * szW);
    bf16_t* xhbt = (bf16_t*)(ws + 3 * szW + szXbt);
    bf16_t* qb   = (bf16_t*)(ws + 3 * szW + szXbt + szXh);
    bf16_t* kb   = (bf16_t*)(ws + 3 * szW + 2 * szXbt + szXh);
    bf16_t* vb   = (bf16_t*)(ws + 3 * szW + 2 * szXbt + 2 * szXh);

    conv_w_kernel<<<768, 256, 0, stream>>>(Wq, Wk, Wv, Wqb, Wkb, Wvb);
    prep_x_kernel<<<dim3(L_ / 64, C_ / 64, B_), 256, 0, stream>>>(x, xbt, xhbt);
    proj_nk_kernel<<<dim3(L_ / 64, B_), 256, 0, stream>>>(xbt, Wqb, bq, qb, L_);
    proj_nk_kernel<<<dim3(M_ / 64, B_), 256, 0, stream>>>(xhbt, Wkb, bk, kb, M_);
    proj_v_kernel<<<dim3(M_ / 256, C_ / 64, B_), 256, 0, stream>>>(xhbt, Wvb, bv, vb);
    attn_kernel<<<256, 512, 0, stream>>>(qb, kb, vb, x, gate, out);
}